// Round 8
// baseline (758.281 us; speedup 1.0000x reference)
//
#include <hip/hip_runtime.h>
#include <hip/hip_bf16.h>

typedef __bf16 bf16x8 __attribute__((ext_vector_type(8)));
typedef __bf16 bf16x4 __attribute__((ext_vector_type(4)));
typedef float  f32x4  __attribute__((ext_vector_type(4)));

#define B_ 4
#define T_ 2048
#define H_ 16
#define D_ 64
#define C_ 1024
#define M_ 8192                    // B*T
#define NE_ ((size_t)M_ * C_)      // elems per (M,C) tensor

// ---------------------------------------------------------------------------
// Probe: flag=1 if inputs are fp32, flag=0 if bf16.
// ---------------------------------------------------------------------------
__global__ void probe_dtype(const unsigned short* __restrict__ x,
                            int* __restrict__ flag)
{
  __shared__ float red[256];
  float m = 0.0f;
  for (int i = threadIdx.x; i < 4096; i += 256) {
    unsigned int u = ((unsigned int)x[i]) << 16;
    float v = fabsf(__uint_as_float(u));
    if (!(v <= 1e30f)) v = 1e31f;
    m = fmaxf(m, v);
  }
  red[threadIdx.x] = m;
  __syncthreads();
  for (int s = 128; s > 0; s >>= 1) {
    if (threadIdx.x < s) red[threadIdx.x] = fmaxf(red[threadIdx.x], red[threadIdx.x + s]);
    __syncthreads();
  }
  if (threadIdx.x == 0) *flag = (red[0] > 100.0f) ? 1 : 0;
}

__device__ __forceinline__ float load1_adapt(const void* p, size_t idx, int f)
{
  if (f) return ((const float*)p)[idx];
  return __bfloat162float(((const __hip_bfloat16*)p)[idx]);
}

// ---------------------------------------------------------------------------
// Convert a tensor to bf16 (fp32 src if flag, else plain bf16 copy).
// ---------------------------------------------------------------------------
__global__ __launch_bounds__(256) void cvt_bf16(
    const int* __restrict__ flagp, const void* __restrict__ src,
    __bf16* __restrict__ dst, int n)
{
  const int f = *flagp;
  for (size_t i = ((size_t)blockIdx.x * 256 + threadIdx.x) * 8; i < (size_t)n;
       i += (size_t)gridDim.x * 2048) {
    bf16x8 r;
    if (f) {
      const float* pf = (const float*)src + i;
      float4 a = *(const float4*)pf;
      float4 b = *(const float4*)(pf + 4);
      r[0] = (__bf16)a.x; r[1] = (__bf16)a.y; r[2] = (__bf16)a.z; r[3] = (__bf16)a.w;
      r[4] = (__bf16)b.x; r[5] = (__bf16)b.y; r[6] = (__bf16)b.z; r[7] = (__bf16)b.w;
    } else {
      r = *(const bf16x8*)((const __bf16*)src + i);
    }
    *(bf16x8*)(dst + i) = r;
  }
}

// ---------------------------------------------------------------------------
// async 16B global -> LDS copy
// ---------------------------------------------------------------------------
__device__ __forceinline__ void g2lds16(const __bf16* g, __bf16* l)
{
  __builtin_amdgcn_global_load_lds(
      (const __attribute__((address_space(1))) void*)g,
      (__attribute__((address_space(3))) void*)l, 16, 0, 0);
}

// ---------------------------------------------------------------------------
// Fused QKV GEMM: [q|k|v] = x @ [Wq;Wk;Wv]^T with fused epilogues:
//   q,k: rmsnorm over head dim + RoPE (in-register; wave n-tile == one head)
//   v:   (1-lamb)*v + lamb*v1
// A: M x K bf16; W: 3C x K bf16 (contiguous). 128x128 tiles, BK=64,
// global_load_lds staging. Grid: (M/128, 3C/128).
// ---------------------------------------------------------------------------
__global__ __launch_bounds__(256) void gemm_qkv(
    const __bf16* __restrict__ A, const __bf16* __restrict__ W,
    __bf16* __restrict__ qout, __bf16* __restrict__ kout,
    __bf16* __restrict__ vout,
    const void* __restrict__ v1, const void* __restrict__ lambp,
    const int* __restrict__ flagp)
{
  __shared__ __bf16 As[128][64];
  __shared__ __bf16 Bs[128][64];

  const int tid  = threadIdx.x;
  const int wv   = tid >> 6;
  const int lane = tid & 63;
  const int n16  = lane & 15;
  const int quad = lane >> 4;
  const int wm = (wv & 1) * 64, wn = (wv >> 1) * 64;
  const int m0  = blockIdx.x * 128;
  const int n0g = blockIdx.y * 128;         // within 3C

  f32x4 acc[4][4];
#pragma unroll
  for (int i = 0; i < 4; i++)
#pragma unroll
    for (int j = 0; j < 4; j++) acc[i][j] = (f32x4){0.f, 0.f, 0.f, 0.f};

  const int trow = tid >> 3;
  const int tcol = (tid & 7) * 8;

  for (int k0 = 0; k0 < C_; k0 += 64) {
#pragma unroll
    for (int p = 0; p < 4; p++) {
      g2lds16(A + (size_t)(m0 + trow + p * 32) * C_ + k0 + tcol,
              &As[trow + p * 32][tcol]);
      g2lds16(W + (size_t)(n0g + trow + p * 32) * C_ + k0 + tcol,
              &Bs[trow + p * 32][tcol]);
    }
    __syncthreads();

#pragma unroll
    for (int kk = 0; kk < 2; kk++) {
      bf16x8 af[4], bf[4];
#pragma unroll
      for (int i = 0; i < 4; i++) {
        af[i] = *(const bf16x8*)&As[wm + i * 16 + n16][kk * 32 + quad * 8];
        bf[i] = *(const bf16x8*)&Bs[wn + i * 16 + n16][kk * 32 + quad * 8];
      }
#pragma unroll
      for (int i = 0; i < 4; i++)
#pragma unroll
        for (int j = 0; j < 4; j++)
          acc[i][j] = __builtin_amdgcn_mfma_f32_16x16x32_bf16(af[i], bf[j],
                                                              acc[i][j], 0, 0, 0);
    }
    __syncthreads();
  }

  const int buf   = blockIdx.y >> 3;                 // 0=q 1=k 2=v
  const int ncol0 = (blockIdx.y & 7) * 128 + wn;     // 64-aligned => head-aligned
  __bf16* dst = (buf == 0) ? qout : (buf == 1) ? kout : vout;

  if (buf < 2) {
    // rmsnorm over head dim (in-thread j-sum + 16-lane shuffle) + RoPE
    const float cfr  = 9.2103403719761836f / 32.0f;  // ln(10000)/32
    const float inv0 = expf(-(float)(n16) * cfr);
    const float inv1 = expf(-(float)(16 + n16) * cfr);
#pragma unroll
    for (int i = 0; i < 4; i++)
#pragma unroll
      for (int r = 0; r < 4; r++) {
        const int row = m0 + wm + i * 16 + quad * 4 + r;
        float x0 = (float)(__bf16)acc[i][0][r];
        float x1 = (float)(__bf16)acc[i][1][r];
        float x2 = (float)(__bf16)acc[i][2][r];
        float x3 = (float)(__bf16)acc[i][3][r];
        float ss = x0 * x0 + x1 * x1 + x2 * x2 + x3 * x3;
        ss += __shfl_xor(ss, 1);
        ss += __shfl_xor(ss, 2);
        ss += __shfl_xor(ss, 4);
        ss += __shfl_xor(ss, 8);
        const float rs = rsqrtf(ss * (1.0f / 64.0f) + 0.0078125f);
        x0 *= rs; x1 *= rs; x2 *= rs; x3 *= rs;
        const float tp = (float)(row & (T_ - 1));
        const float a0 = tp * inv0, a1 = tp * inv1;
        const float c0 = cosf(a0), s0 = sinf(a0);
        const float c1 = cosf(a1), s1 = sinf(a1);
        const float y0 =  x0 * c0 + x2 * s0;
        const float y2 = -x0 * s0 + x2 * c0;
        const float y1 =  x1 * c1 + x3 * s1;
        const float y3 = -x1 * s1 + x3 * c1;
        const size_t base = (size_t)row * C_ + ncol0 + n16;
        dst[base]      = (__bf16)y0;
        dst[base + 16] = (__bf16)y1;
        dst[base + 32] = (__bf16)y2;
        dst[base + 48] = (__bf16)y3;
      }
  } else {
    const int f = *flagp;
    const float lam = load1_adapt(lambp, 0, f);
#pragma unroll
    for (int i = 0; i < 4; i++)
#pragma unroll
      for (int j = 0; j < 4; j++)
#pragma unroll
        for (int r = 0; r < 4; r++) {
          const int row = m0 + wm + i * 16 + quad * 4 + r;
          const size_t idx = (size_t)row * C_ + ncol0 + j * 16 + n16;
          float vv  = (float)(__bf16)acc[i][j][r];
          float v1v = load1_adapt(v1, idx, f);
          dst[idx] = (__bf16)((1.0f - lam) * vv + lam * v1v);
        }
  }
}

// ---------------------------------------------------------------------------
// Plain 128-tile GEMM: C = A * Bm^T (bf16 in; bf16 or fp32 out per flag).
// ---------------------------------------------------------------------------
__global__ __launch_bounds__(256) void gemm128(
    const __bf16* __restrict__ A, const __bf16* __restrict__ Bm,
    void* __restrict__ C, int M, int N, int K,
    const int* __restrict__ flagp, int adaptive)
{
  __shared__ __bf16 As[128][64];
  __shared__ __bf16 Bs[128][64];

  const int tid  = threadIdx.x;
  const int wv   = tid >> 6;
  const int lane = tid & 63;
  const int n16  = lane & 15;
  const int quad = lane >> 4;
  const int wm = (wv & 1) * 64, wn = (wv >> 1) * 64;
  const int m0 = blockIdx.x * 128, n0 = blockIdx.y * 128;

  f32x4 acc[4][4];
#pragma unroll
  for (int i = 0; i < 4; i++)
#pragma unroll
    for (int j = 0; j < 4; j++) acc[i][j] = (f32x4){0.f, 0.f, 0.f, 0.f};

  const int trow = tid >> 3;
  const int tcol = (tid & 7) * 8;

  for (int k0 = 0; k0 < K; k0 += 64) {
#pragma unroll
    for (int p = 0; p < 4; p++) {
      g2lds16(A  + (size_t)(m0 + trow + p * 32) * K + k0 + tcol,
              &As[trow + p * 32][tcol]);
      g2lds16(Bm + (size_t)(n0 + trow + p * 32) * K + k0 + tcol,
              &Bs[trow + p * 32][tcol]);
    }
    __syncthreads();

#pragma unroll
    for (int kk = 0; kk < 2; kk++) {
      bf16x8 af[4], bf[4];
#pragma unroll
      for (int i = 0; i < 4; i++) {
        af[i] = *(const bf16x8*)&As[wm + i * 16 + n16][kk * 32 + quad * 8];
        bf[i] = *(const bf16x8*)&Bs[wn + i * 16 + n16][kk * 32 + quad * 8];
      }
#pragma unroll
      for (int i = 0; i < 4; i++)
#pragma unroll
        for (int j = 0; j < 4; j++)
          acc[i][j] = __builtin_amdgcn_mfma_f32_16x16x32_bf16(af[i], bf[j],
                                                              acc[i][j], 0, 0, 0);
    }
    __syncthreads();
  }

  const int f = adaptive ? *flagp : 0;
  const int rb = quad * 4;
#pragma unroll
  for (int i = 0; i < 4; i++)
#pragma unroll
    for (int j = 0; j < 4; j++)
#pragma unroll
      for (int r = 0; r < 4; r++) {
        const size_t idx = (size_t)(m0 + wm + i * 16 + rb + r) * N
                           + n0 + wn + j * 16 + n16;
        if (f) ((float*)C)[idx] = acc[i][j][r];
        else   ((__bf16*)C)[idx] = (__bf16)acc[i][j][r];
      }
}

// ---------------------------------------------------------------------------
// MFMA flash attention fwd (causal). Q-tile 128/block (2 m-tiles of 16 rows
// per wave), K-tile 64. K/V staging, barriers, and B-fragments shared across
// both m-tiles. y aliases q (block-local slice RAW only).
// ---------------------------------------------------------------------------
__global__ __launch_bounds__(256) void attn_mfma(
    const __bf16* q,
    const __bf16* __restrict__ k,
    const __bf16* __restrict__ v,
    __bf16* y)
{
  __shared__ alignas(16) __bf16 Ks[64][72];        // [s][d]
  __shared__ alignas(16) __bf16 VTs[64][88];       // [d][s]
  __shared__ alignas(16) __bf16 Ps[4][2][16][76];  // per-wave, per-m P tile

  const int tid  = threadIdx.x;
  const int wv   = tid >> 6;
  const int lane = tid & 63;
  const int n16  = lane & 15;
  const int quad = lane >> 4;
  const int b = blockIdx.y >> 4, h = blockIdx.y & 15;
  const int q0 = (int)(gridDim.x - 1 - blockIdx.x) * 128;   // heavy first
  const size_t hb = (size_t)b * T_ * C_ + h * D_;

  // ---- Q fragments for both m-tiles, pre-scaled by 1/8 ----
  bf16x8 aq[2][2];
#pragma unroll
  for (int m = 0; m < 2; m++) {
    const int qrow = q0 + m * 64 + wv * 16 + n16;
    aq[m][0] = *(const bf16x8*)(q + hb + (size_t)qrow * C_ + quad * 8);
    aq[m][1] = *(const bf16x8*)(q + hb + (size_t)qrow * C_ + 32 + quad * 8);
#pragma unroll
    for (int jj = 0; jj < 8; jj++) {
      aq[m][0][jj] = (__bf16)((float)aq[m][0][jj] * 0.125f);
      aq[m][1][jj] = (__bf16)((float)aq[m][1][jj] * 0.125f);
    }
  }

  f32x4 Ot[2][4];
  float m_run[2][4], l_run[2][4];
#pragma unroll
  for (int m = 0; m < 2; m++)
#pragma unroll
    for (int r = 0; r < 4; r++) {
      Ot[m][r] = (f32x4){0.f, 0.f, 0.f, 0.f};
      m_run[m][r] = -1e30f; l_run[m][r] = 0.0f;
    }

  const int niter = q0 / 64 + 2;
  for (int it = 0; it < niter; it++) {
    const int s0 = it * 64;
    // ---- stage K [s][d] ----
    {
      const int r = tid >> 2, c16 = (tid & 3) * 16;
      const __bf16* src = k + hb + (size_t)(s0 + r) * C_ + c16;
      *(bf16x8*)&Ks[r][c16]     = *(const bf16x8*)(src);
      *(bf16x8*)&Ks[r][c16 + 8] = *(const bf16x8*)(src + 8);
    }
    // ---- stage V transposed [d][s] ----
    {
      const int sv = lane;
#pragma unroll
      for (int pp = 0; pp < 2; pp++) {
        const int dblk = wv + pp * 4;
        bf16x8 vv = *(const bf16x8*)(v + hb + (size_t)(s0 + sv) * C_ + dblk * 8);
#pragma unroll
        for (int jj = 0; jj < 8; jj++) VTs[dblk * 8 + jj][sv] = vv[jj];
      }
    }
    __syncthreads();

    // ---- S = Q K^T for both m-tiles (B-frags shared) ----
    f32x4 S[2][4];
#pragma unroll
    for (int t = 0; t < 4; t++) {
      bf16x8 b0 = *(const bf16x8*)&Ks[t * 16 + n16][quad * 8];
      bf16x8 b1 = *(const bf16x8*)&Ks[t * 16 + n16][32 + quad * 8];
#pragma unroll
      for (int m = 0; m < 2; m++) {
        f32x4 z = (f32x4){0.f, 0.f, 0.f, 0.f};
        z = __builtin_amdgcn_mfma_f32_16x16x32_bf16(aq[m][0], b0, z, 0, 0, 0);
        z = __builtin_amdgcn_mfma_f32_16x16x32_bf16(aq[m][1], b1, z, 0, 0, 0);
        S[m][t] = z;
      }
    }

    // ---- causal mask (only near the diagonal; wave-uniform branch) ----
    if (it >= niter - 2) {
#pragma unroll
      for (int m = 0; m < 2; m++)
#pragma unroll
        for (int t = 0; t < 4; t++) {
          const int sg = s0 + t * 16 + n16;
#pragma unroll
          for (int r = 0; r < 4; r++)
            if (sg > q0 + m * 64 + wv * 16 + quad * 4 + r) S[m][t][r] = -1e30f;
        }
    }

    // ---- online softmax (8 independent row-chains) ----
#pragma unroll
    for (int m = 0; m < 2; m++)
#pragma unroll
      for (int r = 0; r < 4; r++) {
        float mx = fmaxf(fmaxf(S[m][0][r], S[m][1][r]),
                         fmaxf(S[m][2][r], S[m][3][r]));
        mx = fmaxf(mx, __shfl_xor(mx, 1));
        mx = fmaxf(mx, __shfl_xor(mx, 2));
        mx = fmaxf(mx, __shfl_xor(mx, 4));
        mx = fmaxf(mx, __shfl_xor(mx, 8));
        const float mnew = fmaxf(m_run[m][r], mx);
        const float al   = __expf(m_run[m][r] - mnew);
        m_run[m][r] = mnew;
        float p0 = __expf(S[m][0][r] - mnew), p1 = __expf(S[m][1][r] - mnew);
        float p2 = __expf(S[m][2][r] - mnew), p3 = __expf(S[m][3][r] - mnew);
        float su = p0 + p1 + p2 + p3;
        su += __shfl_xor(su, 1);
        su += __shfl_xor(su, 2);
        su += __shfl_xor(su, 4);
        su += __shfl_xor(su, 8);
        l_run[m][r] = l_run[m][r] * al + su;
#pragma unroll
        for (int t = 0; t < 4; t++) Ot[m][t][r] *= al;
        const int prow = quad * 4 + r;
        Ps[wv][m][prow][n16]      = (__bf16)p0;
        Ps[wv][m][prow][16 + n16] = (__bf16)p1;
        Ps[wv][m][prow][32 + n16] = (__bf16)p2;
        Ps[wv][m][prow][48 + n16] = (__bf16)p3;
      }

    // ---- O += P V (B-frags shared across m) ----
    bf16x8 ap[2][2];
#pragma unroll
    for (int m = 0; m < 2; m++) {
      bf16x4 l0 = *(const bf16x4*)&Ps[wv][m][n16][quad * 8];
      bf16x4 l1 = *(const bf16x4*)&Ps[wv][m][n16][quad * 8 + 4];
      bf16x4 l2 = *(const bf16x4*)&Ps[wv][m][n16][32 + quad * 8];
      bf16x4 l3 = *(const bf16x4*)&Ps[wv][m][n16][32 + quad * 8 + 4];
      ap[m][0] = __builtin_shufflevector(l0, l1, 0, 1, 2, 3, 4, 5, 6, 7);
      ap[m][1] = __builtin_shufflevector(l2, l3, 0, 1, 2, 3, 4, 5, 6, 7);
    }
#pragma unroll
    for (int t = 0; t < 4; t++) {
      bf16x8 b0 = *(const bf16x8*)&VTs[t * 16 + n16][quad * 8];
      bf16x8 b1 = *(const bf16x8*)&VTs[t * 16 + n16][32 + quad * 8];
#pragma unroll
      for (int m = 0; m < 2; m++) {
        Ot[m][t] = __builtin_amdgcn_mfma_f32_16x16x32_bf16(ap[m][0], b0, Ot[m][t], 0, 0, 0);
        Ot[m][t] = __builtin_amdgcn_mfma_f32_16x16x32_bf16(ap[m][1], b1, Ot[m][t], 0, 0, 0);
      }
    }
    __syncthreads();
  }

  // ---- epilogue ----
#pragma unroll
  for (int m = 0; m < 2; m++) {
    float linv[4];
#pragma unroll
    for (int r = 0; r < 4; r++) linv[r] = 1.0f / l_run[m][r];
    const int orow = q0 + m * 64 + wv * 16 + quad * 4;
#pragma unroll
    for (int t = 0; t < 4; t++)
#pragma unroll
      for (int r = 0; r < 4; r++)
        y[hb + (size_t)(orow + r) * C_ + t * 16 + n16] =
            (__bf16)(Ot[m][t][r] * linv[r]);
  }
}

// ---------------------------------------------------------------------------
__global__ __launch_bounds__(256) void copy_v1(
    const int* __restrict__ flagp, const void* __restrict__ v1, void* __restrict__ out)
{
  const int f = *flagp;
  const size_t nbytes = NE_ * (f ? 4u : 2u);
  const uint4* s = (const uint4*)v1;
  uint4* d = (uint4*)((char*)out + nbytes);
  const size_t n16 = nbytes / 16;
  for (size_t i = (size_t)blockIdx.x * 256 + threadIdx.x; i < n16;
       i += (size_t)gridDim.x * 256)
    d[i] = s[i];
}

// ---------------------------------------------------------------------------
extern "C" void kernel_launch(void* const* d_in, const int* in_sizes, int n_in,
                              void* d_out, int out_size, void* d_ws, size_t ws_size,
                              hipStream_t stream)
{
  const void* x    = d_in[0];
  const void* v1   = d_in[1];
  const void* Wq   = d_in[2];
  const void* Wk   = d_in[3];
  const void* Wv   = d_in[4];
  const void* Wp   = d_in[5];
  const void* lamb = d_in[6];

  // ws layout (bf16): xb | qw | Wq | Wk | Wv | Wp | flag  (~42 MB)
  __bf16* xb  = (__bf16*)d_ws;
  __bf16* qw  = xb + NE_;
  __bf16* wqb = qw + NE_;                  // Wq,Wk,Wv contiguous for gemm_qkv
  __bf16* wkb = wqb + (size_t)C_ * C_;
  __bf16* wvb = wkb + (size_t)C_ * C_;
  __bf16* wpb = wvb + (size_t)C_ * C_;
  int* flagp  = (int*)(wpb + (size_t)C_ * C_);
  // k, v staging in d_out (dead before final writes under both dtypes)
  __bf16* kw = (__bf16*)d_out;
  __bf16* vw = (__bf16*)((char*)d_out + NE_ * 2);

  probe_dtype<<<1, 256, 0, stream>>>((const unsigned short*)x, flagp);

  cvt_bf16<<<4096, 256, 0, stream>>>(flagp, x,  xb,  (int)NE_);
  cvt_bf16<<<512,  256, 0, stream>>>(flagp, Wq, wqb, C_ * C_);
  cvt_bf16<<<512,  256, 0, stream>>>(flagp, Wk, wkb, C_ * C_);
  cvt_bf16<<<512,  256, 0, stream>>>(flagp, Wv, wvb, C_ * C_);
  cvt_bf16<<<512,  256, 0, stream>>>(flagp, Wp, wpb, C_ * C_);

  gemm_qkv<<<dim3(M_ / 128, 24), 256, 0, stream>>>(
      xb, wqb, qw, kw, vw, v1, lamb, flagp);

  attn_mfma<<<dim3(T_ / 128, B_ * H_), 256, 0, stream>>>(qw, kw, vw, qw);

  gemm128<<<dim3(M_ / 128, C_ / 128), 256, 0, stream>>>(
      qw, wpb, d_out, M_, C_, C_, flagp, 1);
  copy_v1<<<8192, 256, 0, stream>>>(flagp, v1, d_out);
}